// Round 2
// baseline (699.568 us; speedup 1.0000x reference)
//
#include <hip/hip_runtime.h>

#define NL 8
#define BPL 524288
#define NB (NL * BPL)            // 4194304 buckets
#define NS 8
#define GRAV 9.8f

// ---------------------------------------------------------------------------
// Single fused kernel: one thread per spigot (NB*NS = 33.5M threads),
// 256 threads/block = 32 buckets/block.
//   - theta dword, S float2, s_q dword store: fully coalesced.
//   - per-bucket outflow: 3-step shfl_xor over the 8 spigot lanes.
//   - inflow[i] = outflow[i-1]: in-block via LDS; the block-boundary bucket's
//     predecessor is RECOMPUTED by threads 0..7 (reads are L2-hot, ~13 MB
//     extra total) instead of round-tripping an outflows[] array through HBM.
//   - H_new written in the same pass (H already in register).
//   - network_outflow: full-wave reduce -> LDS -> 1 atomic per last-layer
//     block (16384 atomics total).
// No workspace usage at all (d_ws untouched).
// 0.5*(tanh(h)+1) == 1/(1+exp(-2h)) -> v_exp + v_rcp instead of tanh.
// ---------------------------------------------------------------------------
__global__ __launch_bounds__(256) void fused_kernel(
    const float* __restrict__ H,
    const float* __restrict__ S,
    const float* __restrict__ theta,
    const float* __restrict__ precip,
    float* __restrict__ s_q,
    float* __restrict__ H_new,
    float* __restrict__ net_out)
{
    const int tid    = blockIdx.x * 256 + threadIdx.x;  // spigot index
    const int bucket = tid >> 3;
    const int lb     = threadIdx.x >> 3;                // local bucket 0..31

    const float  th = theta[tid];
    const float2 sv = reinterpret_cast<const float2*>(S)[tid];  // (height, area)
    const float  Hb = H[bucket];

    const float h   = fmaxf(0.0f, Hb - sv.x);
    const float e   = __expf(-2.0f * h);
    const float mod = __builtin_amdgcn_rcpf(1.0f + e);          // sigmoid(2h)
    const float v   = th * __builtin_amdgcn_sqrtf(2.0f * GRAV * h) * mod;
    const float q   = v * sv.y;

    s_q[tid] = q;

    // ---- per-bucket outflow (8 consecutive lanes) ----
    float sum = q;
    sum += __shfl_xor(sum, 1);
    sum += __shfl_xor(sum, 2);
    sum += __shfl_xor(sum, 4);

    __shared__ float bsum[33];   // [0] = inflow of block's first bucket
    __shared__ float wsum[4];
    if ((threadIdx.x & 7) == 0) bsum[lb + 1] = sum;

    // ---- network_outflow partial (block fully inside last layer or not) ----
    const bool last_layer = (blockIdx.x >= ((NB - BPL) >> 5));
    if (last_layer) {
        // sum is uniform within each 8-lane group -> 3 more xors = wave total
        float part = sum;
        part += __shfl_xor(part, 8);
        part += __shfl_xor(part, 16);
        part += __shfl_xor(part, 32);
        if ((threadIdx.x & 63) == 0) wsum[threadIdx.x >> 6] = part;
    }

    // ---- boundary: recompute previous block's last bucket outflow ----
    if (threadIdx.x < 8) {
        float pq;
        if (blockIdx.x > 0) {
            const int   pidx = blockIdx.x * 256 - 8 + threadIdx.x;
            const float pth  = theta[pidx];
            const float2 psv = reinterpret_cast<const float2*>(S)[pidx];
            const float pH   = H[pidx >> 3];
            const float ph   = fmaxf(0.0f, pH - psv.x);
            const float pe   = __expf(-2.0f * ph);
            const float pmod = __builtin_amdgcn_rcpf(1.0f + pe);
            const float pv   = pth * __builtin_amdgcn_sqrtf(2.0f * GRAV * ph) * pmod;
            pq = pv * psv.y;
        } else {
            pq = (threadIdx.x == 0) ? precip[0] : 0.0f;  // bucket 0: inflow = precip
        }
        // xor 1,2,4 stays within lanes 0..7 (all active here)
        pq += __shfl_xor(pq, 1);
        pq += __shfl_xor(pq, 2);
        pq += __shfl_xor(pq, 4);
        if (threadIdx.x == 0) bsum[0] = pq;
    }

    __syncthreads();

    if ((threadIdx.x & 7) == 0) {
        H_new[bucket] = Hb + bsum[lb] - bsum[lb + 1];
    }

    if (last_layer && threadIdx.x == 0) {
        atomicAdd(net_out, (wsum[0] + wsum[1]) + (wsum[2] + wsum[3]));
    }
}

extern "C" void kernel_launch(void* const* d_in, const int* in_sizes, int n_in,
                              void* d_out, int out_size, void* d_ws, size_t ws_size,
                              hipStream_t stream) {
    const float* H      = (const float*)d_in[0];   // [NB]
    const float* S      = (const float*)d_in[1];   // [NB, NS, 2]
    const float* theta  = (const float*)d_in[2];   // [NB*NS]
    const float* precip = (const float*)d_in[3];   // scalar

    float* out     = (float*)d_out;
    float* H_new   = out;                               // [NB]
    float* s_q     = out + NB;                          // [NB, NS]
    float* net_out = out + NB + (size_t)NB * NS;        // scalar

    // scalar slot is poisoned 0xAA each run -> zero it (capture-safe memset)
    hipMemsetAsync(net_out, 0, sizeof(float), stream);

    fused_kernel<<<(NB * NS) / 256, 256, 0, stream>>>(
        H, S, theta, precip, s_q, H_new, net_out);
}

// Round 3
// 492.596 us; speedup vs baseline: 1.4202x; 1.4202x over previous
//
#include <hip/hip_runtime.h>

#define NL 8
#define BPL 524288
#define NB (NL * BPL)            // 4194304 buckets
#define NS 8
#define GRAV 9.8f

// 0.5*(tanh(h)+1) == 1/(1+exp(-2h)) -> sigmoid(2h) via v_exp + v_rcp.
__device__ __forceinline__ float spigot_q(float th, float hgt, float area, float Hb) {
    const float h   = fmaxf(0.0f, Hb - hgt);
    const float e   = __expf(-2.0f * h);
    const float mod = __builtin_amdgcn_rcpf(1.0f + e);
    return th * __builtin_amdgcn_sqrtf(2.0f * GRAV * h) * mod * area;
}

// ---------------------------------------------------------------------------
// Wave-autonomous, one thread per BUCKET (NB = 4.2M threads, 16384 blocks).
//   - Per thread: 2x float4 theta, 4x float4 S, 1x float H -> 7 independent
//     loads issued at kernel top (single latency hop, 8-way spigot ILP).
//   - Boundary loads (lanes 0..7 recompute the wave-predecessor bucket's
//     spigots) are ALSO hoisted to the top -> no chained latency.
//   - inflow = __shfl_up(outflow, 1); lane 0 takes the recomputed boundary
//     outflow (or precip for bucket 0). No LDS / no barrier on main path.
//   - s_q written as 2x float4 per thread (write-combined in L2).
//   - net_out: only the 2048 last-layer blocks reduce (wave shfl -> LDS ->
//     one atomic per block). Branch is block-uniform (NB-BPL = 14336*256).
// d_ws untouched (ws poison is unconditional anyway; fills ~340us fixed).
// ---------------------------------------------------------------------------
__global__ __launch_bounds__(256) void fused_kernel(
    const float* __restrict__ H,
    const float* __restrict__ S,
    const float* __restrict__ theta,
    const float* __restrict__ precip,
    float* __restrict__ s_q,
    float* __restrict__ H_new,
    float* __restrict__ net_out)
{
    const int bucket = blockIdx.x * 256 + threadIdx.x;
    const int lane   = threadIdx.x & 63;
    const int wbase  = bucket - lane;            // first bucket of this wave

    // ---- hoisted boundary loads: lanes 0..7 fetch bucket (wbase-1)'s data ----
    float  pth = 0.0f, pH = 0.0f, pre = 0.0f;
    float2 psv = make_float2(0.0f, 0.0f);
    if (wbase > 0) {
        if (lane < 8) {
            const int pidx = (wbase - 1) * 8 + lane;
            pth = theta[pidx];
            psv = reinterpret_cast<const float2*>(S)[pidx];
            pH  = H[wbase - 1];
        }
    } else if (lane == 0) {
        pre = precip[0];
    }

    // ---- main loads: all independent, issued back-to-back ----
    const float  Hb = H[bucket];
    const float4 t0 = reinterpret_cast<const float4*>(theta)[bucket * 2];
    const float4 t1 = reinterpret_cast<const float4*>(theta)[bucket * 2 + 1];
    const float4 s0 = reinterpret_cast<const float4*>(S)[bucket * 4];
    const float4 s1 = reinterpret_cast<const float4*>(S)[bucket * 4 + 1];
    const float4 s2 = reinterpret_cast<const float4*>(S)[bucket * 4 + 2];
    const float4 s3 = reinterpret_cast<const float4*>(S)[bucket * 4 + 3];

    // ---- 8 spigots, fully unrolled (static indexing only) ----
    const float q0 = spigot_q(t0.x, s0.x, s0.y, Hb);
    const float q1 = spigot_q(t0.y, s0.z, s0.w, Hb);
    const float q2 = spigot_q(t0.z, s1.x, s1.y, Hb);
    const float q3 = spigot_q(t0.w, s1.z, s1.w, Hb);
    const float q4 = spigot_q(t1.x, s2.x, s2.y, Hb);
    const float q5 = spigot_q(t1.y, s2.z, s2.w, Hb);
    const float q6 = spigot_q(t1.z, s3.x, s3.y, Hb);
    const float q7 = spigot_q(t1.w, s3.z, s3.w, Hb);

    reinterpret_cast<float4*>(s_q)[bucket * 2]     = make_float4(q0, q1, q2, q3);
    reinterpret_cast<float4*>(s_q)[bucket * 2 + 1] = make_float4(q4, q5, q6, q7);

    const float of = ((q0 + q1) + (q2 + q3)) + ((q4 + q5) + (q6 + q7));

    // ---- boundary outflow: lanes 0..7 hold prev bucket's spigot q's ----
    float pq = spigot_q(pth, psv.x, psv.y, pH);   // 0 for lanes >= 8
    pq += __shfl_xor(pq, 1);
    pq += __shfl_xor(pq, 2);
    pq += __shfl_xor(pq, 4);                       // lane 0: prev-bucket outflow

    const float prev   = __shfl_up(of, 1);         // lanes 1..63
    const float inflow = (lane == 0) ? ((wbase == 0) ? pre : pq) : prev;

    H_new[bucket] = Hb + inflow - of;

    // ---- network outflow over last layer (block-uniform branch) ----
    if (bucket >= NB - BPL) {
        float part = of;
        part += __shfl_xor(part, 1);
        part += __shfl_xor(part, 2);
        part += __shfl_xor(part, 4);
        part += __shfl_xor(part, 8);
        part += __shfl_xor(part, 16);
        part += __shfl_xor(part, 32);

        __shared__ float wsum[4];
        if (lane == 0) wsum[threadIdx.x >> 6] = part;
        __syncthreads();
        if (threadIdx.x == 0) {
            atomicAdd(net_out, (wsum[0] + wsum[1]) + (wsum[2] + wsum[3]));
        }
    }
}

extern "C" void kernel_launch(void* const* d_in, const int* in_sizes, int n_in,
                              void* d_out, int out_size, void* d_ws, size_t ws_size,
                              hipStream_t stream) {
    const float* H      = (const float*)d_in[0];   // [NB]
    const float* S      = (const float*)d_in[1];   // [NB, NS, 2]
    const float* theta  = (const float*)d_in[2];   // [NB*NS]
    const float* precip = (const float*)d_in[3];   // scalar

    float* out     = (float*)d_out;
    float* H_new   = out;                               // [NB]
    float* s_q     = out + NB;                          // [NB, NS]
    float* net_out = out + NB + (size_t)NB * NS;        // scalar

    // scalar slot is poisoned 0xAA each run -> zero it (capture-safe memset)
    hipMemsetAsync(net_out, 0, sizeof(float), stream);

    fused_kernel<<<NB / 256, 256, 0, stream>>>(
        H, S, theta, precip, s_q, H_new, net_out);
}